// Round 7
// baseline (200.913 us; speedup 1.0000x reference)
//
#include <hip/hip_runtime.h>
#include <math.h>

#define Bb 8
#define Nn 64
#define Ff 32
#define Tt 4
#define OUTn 128
#define NPAIR 2016   // 64*63/2 lower-triangle pairs (i>j)

__device__ __forceinline__ float sigmoidf_(float x){ return 1.0f/(1.0f+expf(-x)); }

__device__ __forceinline__ void p2ij(int p, int& i, int& j){
  int ii = (int)((1.0f + sqrtf(1.0f + 8.0f*(float)p)) * 0.5f);
  while (ii*(ii-1)/2 > p) --ii;
  while ((ii+1)*ii/2 <= p) ++ii;
  i = ii; j = p - ii*(ii-1)/2;
}

// sequential-order fp32 dot (bit-identical to the validated round-0 ordering;
// the floor(sigmoid) gate is discontinuous -> this order must not change)
__device__ __forceinline__ float dot32(const float4* __restrict__ u, const float* __restrict__ v){
  const float4* v4 = (const float4*)v;
  float d = 0.f;
#pragma unroll
  for (int q=0;q<8;++q){
    float4 a=u[q], b=v4[q];
    d = fmaf(a.x,b.x,d); d = fmaf(a.y,b.y,d);
    d = fmaf(a.z,b.z,d); d = fmaf(a.w,b.w,d);
  }
  return d;
}

// static float4-component extract (g compile-time under full unroll)
#define VCE(arr,g) ((g&3)==0 ? arr[(g)>>2].x : (g&3)==1 ? arr[(g)>>2].y : \
                    (g&3)==2 ? arr[(g)>>2].z : arr[(g)>>2].w)

// ---- precompute: wz/wc = W.x + bias in pair layout [p][b][f]; fused t=0:
//      mf0 = sigmoid(wz)*tanh(wc) for ALL pairs; per-(p,b) row norms ----
__global__ __launch_bounds__(64) void precompute_pair(
    const float* __restrict__ x,
    const float* __restrict__ w_z,
    const float* __restrict__ w_c,
    const float* __restrict__ b_z,
    const float* __restrict__ b_c,
    float* __restrict__ wz,
    float* __restrict__ wc,
    float* __restrict__ mf0,
    float* __restrict__ nrm0) {
  int p = blockIdx.x;
  int i, j; p2ij(p, i, j);
  int l = threadIdx.x, f = l & 31, h = l >> 5;

  __shared__ __align__(16) float xL[Bb][Ff];
  __shared__ __align__(16) float valL[2][Bb][Ff];
  for (int q = l; q < Bb*Ff; q += 64) {
    int b = q >> 5, g = q & 31;
    xL[b][g] = x[(b*Nn + i)*Ff + g];
  }
  __syncthreads();

  const float* W = h ? w_c : w_z;
  const float4* w4 = (const float4*)&W[(((size_t)i*Nn + j)*Ff + f)*Ff];
  float4 w[8];
#pragma unroll
  for (int q=0;q<8;++q) w[q]=w4[q];
  float bias = h ? b_c[f] : b_z[f];
  float* dst = h ? wc : wz;
#pragma unroll
  for (int b=0;b<Bb;++b){
    float v = dot32(w, xL[b]) + bias;
    dst[(size_t)p*256 + b*32 + f] = v;
    valL[h][b][f] = v;
  }
  __syncthreads();
#pragma unroll
  for (int b=0;b<Bb;++b){
    float mfv = sigmoidf_(valL[0][b][f]) * tanhf(valL[1][b][f]);
    if (h == 0) mf0[(size_t)p*256 + b*32 + f] = mfv;
    float ss = mfv*mfv;
    ss += __shfl_xor(ss,1); ss += __shfl_xor(ss,2); ss += __shfl_xor(ss,4);
    ss += __shfl_xor(ss,8); ss += __shfl_xor(ss,16);
    if (l == 0) nrm0[p*8 + b] = sqrtf(ss);
  }
}

// ---- per (b,i): agg row (strict ascending-k fmaf chain, zeros included,
//      matching the reference einsum) + nmax = max_k-in-nbr ||M row|| ----
__global__ __launch_bounds__(64) void gather_agg(
    const float* __restrict__ A,
    const float* __restrict__ mf,
    const float* __restrict__ nrm,
    float* __restrict__ agg,
    float* __restrict__ nmax) {
  int bi = blockIdx.x;
  int b = bi >> 6, i = bi & 63;
  int l = threadIdx.x, f = l & 31, h = l >> 5;
  const float* Ar = &A[(b*Nn + i)*Nn];
  if (h == 0) {
    float acc = 0.f;
#pragma unroll 8
    for (int k = 0; k < Nn; ++k) {
      int hi = i > k ? i : k, lo = i > k ? k : i;
      int pk = (k == i) ? 0 : (hi*(hi-1)/2 + lo);
      float a = Ar[k];
      float v = mf[(size_t)pk*256 + b*32 + f];
      acc = fmaf(a, v, acc);   // a==0 terms are exact no-ops (reference order)
    }
    agg[(b*Nn + i)*Ff + f] = acc;
  } else {
    float m = 0.f;
#pragma unroll
    for (int t2 = 0; t2 < 2; ++t2) {
      int k = f + 32*t2;
      int hi = i > k ? i : k, lo = i > k ? k : i;
      int pk = (k == i) ? 0 : (hi*(hi-1)/2 + lo);
      float a = Ar[k];
      float nv = nrm[pk*8 + b];
      if (a != 0.f) m = fmaxf(m, nv);
    }
    m = fmaxf(m, __shfl_xor(m,1));  m = fmaxf(m, __shfl_xor(m,2));
    m = fmaxf(m, __shfl_xor(m,4));  m = fmaxf(m, __shfl_xor(m,8));
    m = fmaxf(m, __shfl_xor(m,16));
    if (f == 0) nmax[b*Nn + i] = m;
  }
}

// ---- one MP iteration (t>=1): grid = pairs, barrier-free, LDS-free.
//      wave w handles b = 2w + halfwave; lane layout (h,f) ----
__global__ __launch_bounds__(256) void edge_update(
    const float* __restrict__ A,
    const float* __restrict__ u_z,
    const float* __restrict__ u_c,
    const float* __restrict__ wz,
    const float* __restrict__ wc,
    const float* __restrict__ agg,
    const float* __restrict__ nmax,
    const float* __restrict__ mfp,
    const float* __restrict__ nrmp,
    float* __restrict__ mfn,
    float* __restrict__ nrmn) {
  int p = blockIdx.x;
  int i, j; p2ij(p, i, j);
  int tid = threadIdx.x;
  int w = tid >> 6, lane = tid & 63, h = lane >> 5, f = lane & 31;
  int b = w*2 + h;
  int h32 = lane & 32;
  size_t pb = (size_t)p*256 + b*32;

  // adjacency mask of center i for this b
  float a0 = A[(b*Nn + i)*Nn + f];
  float a1 = A[(b*Nn + i)*Nn + 32 + f];
  unsigned long long bal0 = __ballot(a0 != 0.f);
  unsigned long long bal1 = __ballot(a1 != 0.f);
  unsigned int m0 = (unsigned int)(bal0 >> h32);
  unsigned int m1 = (unsigned int)(bal1 >> h32);
  unsigned long long kadj = (unsigned long long)m0 | ((unsigned long long)m1 << 32);
  bool edge = (kadj >> j) & 1;

  float z = 0.f, mo_f = 0.f, wcf = 0.f, gs = 0.f, d2 = 0.f;
  float wb = -1.0e30f, un = 0.f;
  float4 u[8];
  if (edge) {
    const float4* u4 = (const float4*)&u_z[(((size_t)i*Nn + j)*Ff + f)*Ff];
#pragma unroll
    for (int q=0;q<8;++q) u[q] = u4[q];
    wb  = wz[pb + f];
    wcf = wc[pb + f];
#pragma unroll
    for (int q=0;q<8;++q){
      float4 a=u[q];
      un = fmaf(a.x,a.x,un); un = fmaf(a.y,a.y,un);
      un = fmaf(a.z,a.z,un); un = fmaf(a.w,a.w,un);
    }
    un = sqrtf(un);
    // z = sigmoid(wb + u . (agg - mf_prev))   (broadcast row loads)
    const float4* ag4 = (const float4*)(agg + (size_t)(b*Nn + i)*Ff);
    const float4* mp4 = (const float4*)(mfp + pb);
    float d = 0.f;
#pragma unroll
    for (int q=0;q<8;++q){
      float4 ag = ag4[q], mm = mp4[q];
      float mx = ag.x - mm.x, my = ag.y - mm.y, mz = ag.z - mm.z, mw = ag.w - mm.w;
      d = fmaf(u[q].x,mx,d); d = fmaf(u[q].y,my,d);
      d = fmaf(u[q].z,mz,d); d = fmaf(u[q].w,mw,d);
    }
    z = sigmoidf_(wb + d);
    mo_f = agg[(b*Nn + i)*Ff + f] - mfp[pb + f];
  }

  // outer Cauchy-Schwarz screen (one ballot; half-uniform decision)
  float nmx = nmax[b*Nn + i];
  unsigned long long fb = __ballot(edge && (wb + un*nmx >= 15.5f));
  bool fired = ((fb >> h32) & 0xFFFFFFFFull) != 0ull;

  if (fired) {
    unsigned long long kk = kadj & ~(1ull << j);
    while (kk) {
      int k = __builtin_ctzll(kk);
      kk &= kk - 1;
      int hi = i > k ? i : k, lo = i > k ? k : i;
      int pk = hi*(hi-1)/2 + lo;
      float nk = nrmp[pk*8 + b];
      unsigned long long sb = __ballot(wb + un*nk >= 15.5f);
      if (((sb >> h32) & 0xFFFFFFFFull) != 0ull) {
        const float4* mk4 = (const float4*)(mfp + (size_t)pk*256 + b*32);
        float dd = 0.f;
#pragma unroll
        for (int q=0;q<8;++q){
          float4 m = mk4[q];
          dd = fmaf(u[q].x,m.x,dd); dd = fmaf(u[q].y,m.y,dd);
          dd = fmaf(u[q].z,m.z,dd); dd = fmaf(u[q].w,m.w,dd);
        }
        float v = wb + dd;
        if (v >= 16.0f && (v > 17.5f || sigmoidf_(v) >= 1.0f))
          gs += mfp[(size_t)pk*256 + b*32 + f];
      }
    }
  }

  // rare fire path: r_msg and second u_c dot via in-half shuffles
  unsigned long long gb = __ballot(gs != 0.0f);
  bool rf = ((gb >> h32) & 0xFFFFFFFFull) != 0ull;
  if (rf) {
    float4 uc[8];
    const float4* uc4 = (const float4*)&u_c[(((size_t)i*Nn + j)*Ff + f)*Ff];
#pragma unroll
    for (int q=0;q<8;++q) uc[q]=uc4[q];
    float rm = 0.f;
#pragma unroll
    for (int g = 0; g < 32; ++g)
      rm = fmaf(VCE(uc,g), __shfl(gs, h32 + g), rm);
    float dd2 = 0.f;
#pragma unroll
    for (int g = 0; g < 32; ++g)
      dd2 = fmaf(VCE(uc,g), __shfl(rm, h32 + g), dd2);
    d2 = dd2;
  }

  float mfv = 0.f;
  if (edge) {
    float cur = tanhf(wcf + d2);
    mfv = (1.0f - z)*mo_f + z*cur;
  }
  mfn[pb + f] = mfv;
  float ss = mfv*mfv;
  ss += __shfl_xor(ss,1); ss += __shfl_xor(ss,2); ss += __shfl_xor(ss,4);
  ss += __shfl_xor(ss,8); ss += __shfl_xor(ss,16);
  if (f == 0) nrmn[p*8 + b] = sqrtf(ss);
}

// ---- enc = relu(u_node.x + u_msg.msg_sum); msg_sum == agg of final mf ----
__global__ __launch_bounds__(64) void finalize_enc(
    const float* __restrict__ x,
    const float* __restrict__ agg,
    const float* __restrict__ u_node,
    const float* __restrict__ u_msg,
    float* __restrict__ enc) {
  int bi = blockIdx.x;
  int b = bi >> 6, i = bi & 63;
  int l = threadIdx.x, f = l & 31, h = l >> 5;
  __shared__ __align__(16) float vecL[2][Ff];
  if (l < 32)      vecL[0][l]      = x[(b*Nn + i)*Ff + l];
  else             vecL[1][l - 32] = agg[(b*Nn + i)*Ff + (l - 32)];
  __syncthreads();
  const float* Urow = (h == 0) ? &u_node[((size_t)i*Ff + f)*Ff]
                               : &u_msg [((size_t)i*Ff + f)*Ff];
  const float4* w4 = (const float4*)Urow;
  float4 w[8];
#pragma unroll
  for (int q=0;q<8;++q) w[q]=w4[q];
  float d = dot32(w, vecL[h]);
  float dO = __shfl(d, l ^ 32);
  if (l < 32) enc[(b*Nn + i)*Ff + f] = fmaxf(d + dO, 0.0f);
}

// ---- output linear + sigmoid: one wave per (b, o) ----
__global__ __launch_bounds__(64) void linear_out(
    const float* __restrict__ enc,
    const float* __restrict__ lin_w,
    const float* __restrict__ lin_b,
    float* __restrict__ out) {
  int b = blockIdx.x >> 7;
  int o = blockIdx.x & 127;
  int l = threadIdx.x;
  const float4* w4 = (const float4*)&lin_w[(size_t)o*(Nn*Ff)];
  const float4* e4 = (const float4*)&enc[(size_t)b*(Nn*Ff)];
  float acc = 0.f;
#pragma unroll
  for (int q = 0; q < 8; ++q) {
    float4 w = w4[q*64 + l], e = e4[q*64 + l];
    acc = fmaf(w.x,e.x,acc); acc = fmaf(w.y,e.y,acc);
    acc = fmaf(w.z,e.z,acc); acc = fmaf(w.w,e.w,acc);
  }
  acc += __shfl_xor(acc, 1);  acc += __shfl_xor(acc, 2);
  acc += __shfl_xor(acc, 4);  acc += __shfl_xor(acc, 8);
  acc += __shfl_xor(acc, 16); acc += __shfl_xor(acc, 32);
  if (l == 0) out[b*OUTn + o] = sigmoidf_(acc + lin_b[o]);
}

extern "C" void kernel_launch(void* const* d_in, const int* in_sizes, int n_in,
                              void* d_out, int out_size, void* d_ws, size_t ws_size,
                              hipStream_t stream) {
  const float* x      = (const float*)d_in[0];
  const float* A      = (const float*)d_in[1];
  const float* w_z    = (const float*)d_in[2];
  const float* w_c    = (const float*)d_in[3];
  const float* u_z    = (const float*)d_in[4];
  const float* u_c    = (const float*)d_in[5];
  const float* b_z    = (const float*)d_in[6];
  const float* b_c    = (const float*)d_in[7];
  const float* u_node = (const float*)d_in[8];
  const float* u_msg  = (const float*)d_in[9];
  const float* lin_w  = (const float*)d_in[10];
  const float* lin_b  = (const float*)d_in[11];
  float* out = (float*)d_out;
  float* ws  = (float*)d_ws;

  const size_t PB = (size_t)NPAIR * 256;    // 516096 floats
  float* wz   = ws;
  float* wc   = wz   + PB;
  float* mf0  = wc   + PB;
  float* mf1  = mf0  + PB;
  float* nrm0 = mf1  + PB;                  // NPAIR*8
  float* nrm1 = nrm0 + (size_t)NPAIR*8;
  float* agg  = nrm1 + (size_t)NPAIR*8;     // 8*64*32
  float* nmax = agg  + (size_t)Bb*Nn*Ff;    // 8*64
  float* enc  = nmax + (size_t)Bb*Nn;       // 8*64*32

  precompute_pair<<<NPAIR, 64, 0, stream>>>(x, w_z, w_c, b_z, b_c,
                                            wz, wc, mf0, nrm0);

  float* mfR = mf0;  float* nrR = nrm0;
  float* mfW = mf1;  float* nrW = nrm1;
  for (int t = 1; t < Tt; ++t) {
    gather_agg<<<Bb*Nn, 64, 0, stream>>>(A, mfR, nrR, agg, nmax);
    edge_update<<<NPAIR, 256, 0, stream>>>(A, u_z, u_c, wz, wc, agg, nmax,
                                           mfR, nrR, mfW, nrW);
    float* tm = mfR; mfR = mfW; mfW = tm;
    float* tn = nrR; nrR = nrW; nrW = tn;
  }
  gather_agg<<<Bb*Nn, 64, 0, stream>>>(A, mfR, nrR, agg, nmax);  // msg_sum
  finalize_enc<<<Bb*Nn, 64, 0, stream>>>(x, agg, u_node, u_msg, enc);
  linear_out<<<Bb*OUTn, 64, 0, stream>>>(enc, lin_w, lin_b, out);
}

// Round 8
// 181.362 us; speedup vs baseline: 1.1078x; 1.1078x over previous
//
#include <hip/hip_runtime.h>
#include <math.h>

#define Bb 8
#define Nn 64
#define Ff 32
#define Tt 4
#define OUTn 128
#define NPAIR 2016   // 64*63/2 lower-triangle pairs (i>j)

__device__ __forceinline__ float sigmoidf_(float x){ return 1.0f/(1.0f+expf(-x)); }

__device__ __forceinline__ void p2ij(int p, int& i, int& j){
  int ii = (int)((1.0f + sqrtf(1.0f + 8.0f*(float)p)) * 0.5f);
  while (ii*(ii-1)/2 > p) --ii;
  while ((ii+1)*ii/2 <= p) ++ii;
  i = ii; j = p - ii*(ii-1)/2;
}

// sequential-order fp32 dot (bit-identical to the validated round-0 ordering;
// the floor(sigmoid) gate is discontinuous -> this order must not change)
__device__ __forceinline__ float dot32(const float4* __restrict__ u, const float* __restrict__ v){
  const float4* v4 = (const float4*)v;
  float d = 0.f;
#pragma unroll
  for (int q=0;q<8;++q){
    float4 a=u[q], b=v4[q];
    d = fmaf(a.x,b.x,d); d = fmaf(a.y,b.y,d);
    d = fmaf(a.z,b.z,d); d = fmaf(a.w,b.w,d);
  }
  return d;
}

// static float4-component extract (g compile-time under full unroll)
#define VCE(arr,g) ((g&3)==0 ? arr[(g)>>2].x : (g&3)==1 ? arr[(g)>>2].y : \
                    (g&3)==2 ? arr[(g)>>2].z : arr[(g)>>2].w)

// ---- precompute (lower-tri pairs): wzxb/wcxb [b,i,j,f], fused t=0 mf0,
//      per-(p,b) row norms, unfmax[p] = max_f ||u_z[i,j,f,:]|| ----
__global__ __launch_bounds__(64) void precompute_pair(
    const float* __restrict__ x,
    const float* __restrict__ w_z,
    const float* __restrict__ w_c,
    const float* __restrict__ u_z,
    const float* __restrict__ b_z,
    const float* __restrict__ b_c,
    float* __restrict__ wzxb,
    float* __restrict__ wcxb,
    float* __restrict__ mf0,
    float* __restrict__ nrm0,
    float* __restrict__ unfmax) {
  int p = blockIdx.x;
  int i, j; p2ij(p, i, j);
  int l = threadIdx.x, f = l & 31, h = l >> 5;

  __shared__ __align__(16) float xL[Bb][Ff];
  __shared__ __align__(16) float valL[2][Bb][Ff];
  for (int q = l; q < Bb*Ff; q += 64) {
    int b = q >> 5, g = q & 31;
    xL[b][g] = x[(b*Nn + i)*Ff + g];
  }
  __syncthreads();

  const float* W = h ? w_c : w_z;
  const float4* w4 = (const float4*)&W[(((size_t)i*Nn + j)*Ff + f)*Ff];
  float4 w[8];
#pragma unroll
  for (int q=0;q<8;++q) w[q]=w4[q];
  float bias = h ? b_c[f] : b_z[f];
  float* dst = h ? wcxb : wzxb;
#pragma unroll
  for (int b=0;b<Bb;++b){
    float v = dot32(w, xL[b]) + bias;
    dst[((size_t)(b*Nn + i)*Nn + j)*Ff + f] = v;
    valL[h][b][f] = v;
  }
  __syncthreads();
  // t=0: m_full0 = sigmoid(wzxb)*tanh(wcxb)  (bit-exact; M=0 at t=0)
#pragma unroll
  for (int b=0;b<Bb;++b){
    float mfv = sigmoidf_(valL[0][b][f]) * tanhf(valL[1][b][f]);
    if (h == 0) mf0[((size_t)(b*Nn + i)*Nn + j)*Ff + f] = mfv;
    float ss = mfv*mfv;
    ss += __shfl_xor(ss,1); ss += __shfl_xor(ss,2); ss += __shfl_xor(ss,4);
    ss += __shfl_xor(ss,8); ss += __shfl_xor(ss,16);
    if (l == 0) nrm0[p*8 + b] = sqrtf(ss);
  }
  // unfmax[p] = max_f ||u_z[i,j,f,:]|| (screening bound, iteration-invariant)
  if (h == 0) {
    const float4* u4 = (const float4*)&u_z[(((size_t)i*Nn + j)*Ff + f)*Ff];
    float ss = 0.f;
#pragma unroll
    for (int q=0;q<8;++q){
      float4 v = u4[q];
      ss = fmaf(v.x,v.x,ss); ss = fmaf(v.y,v.y,ss);
      ss = fmaf(v.z,v.z,ss); ss = fmaf(v.w,v.w,ss);
    }
    ss = fmaxf(ss, __shfl_xor(ss,1));  ss = fmaxf(ss, __shfl_xor(ss,2));
    ss = fmaxf(ss, __shfl_xor(ss,4));  ss = fmaxf(ss, __shfl_xor(ss,8));
    ss = fmaxf(ss, __shfl_xor(ss,16));
    if (f == 0) unfmax[p] = sqrtf(ss);
  }
}

// ---- per (b,i): agg row (strict ascending-k fmaf chain, matches reference
//      einsum incl. exact zero terms) + nmax = max over nbrs of ||M row|| ----
__global__ __launch_bounds__(64) void gather_agg(
    const float* __restrict__ A,
    const float* __restrict__ mf,
    const float* __restrict__ nrm,
    float* __restrict__ agg,
    float* __restrict__ nmax) {
  int bi = blockIdx.x;
  int b = bi >> 6, i = bi & 63;
  int l = threadIdx.x, f = l & 31, h = l >> 5;
  const float* Ar = &A[(b*Nn + i)*Nn];
  if (h == 0) {
    float acc = 0.f;
#pragma unroll 8
    for (int k = 0; k < Nn; ++k) {
      int hi = i > k ? i : k, lo = i > k ? k : i;
      float a = Ar[k];
      float v = mf[((size_t)(b*Nn + hi)*Nn + lo)*Ff + f];
      acc = fmaf(a, v, acc);   // a==0 terms exact no-ops (reference order)
    }
    agg[(b*Nn + i)*Ff + f] = acc;
  } else {
    float m = 0.f;
#pragma unroll
    for (int t2 = 0; t2 < 2; ++t2) {
      int k = f + 32*t2;
      int hi = i > k ? i : k, lo = i > k ? k : i;
      int pk = (k == i) ? 0 : (hi*(hi-1)/2 + lo);
      float a = Ar[k];
      float nv = nrm[pk*8 + b];
      if (a != 0.f) m = fmaxf(m, nv);
    }
    m = fmaxf(m, __shfl_xor(m,1));  m = fmaxf(m, __shfl_xor(m,2));
    m = fmaxf(m, __shfl_xor(m,4));  m = fmaxf(m, __shfl_xor(m,8));
    m = fmaxf(m, __shfl_xor(m,16));
    if (f == 0) nmax[b*Nn + i] = m;
  }
}

// ---- one MP iteration (t>=1): block=(b,i,jh), skeleton-free.
//      Half-wave owns one (j,f-group); j-screen precomputed; no Mc staging ----
__global__ __launch_bounds__(256) void edge_update(
    const float* __restrict__ A,
    const float* __restrict__ u_z,
    const float* __restrict__ u_c,
    const float* __restrict__ wzxb,
    const float* __restrict__ wcxb,
    const float* __restrict__ unfmax,
    const float* __restrict__ agg,
    const float* __restrict__ nmax,
    const float* __restrict__ mfp,
    const float* __restrict__ nrmp,
    float* __restrict__ mfn,
    float* __restrict__ nrmn) {
  int b  = blockIdx.x;   // 8
  int i  = blockIdx.y;   // 64
  int jh = blockIdx.z;   // 2
  int tid = threadIdx.x;
  int f = tid & 31;
  int h32 = tid & 32;

  __shared__ int jlistL[32];
  __shared__ unsigned int kadjLo, kadjHi;
  __shared__ int jcL;

  if (tid < 64) {
    float a = A[(b*Nn + i)*Nn + tid];
    bool e = (a != 0.0f);
    unsigned long long m = __ballot(e);
    bool ej = e && (tid < i);
    unsigned long long mj = __ballot(ej);
    if (ej) {
      int r = __popcll(mj & ((1ull << tid) - 1ull));
      if ((r & 1) == jh) jlistL[r >> 1] = tid;
    }
    if (tid == 0) {
      kadjLo = (unsigned int)m;
      kadjHi = (unsigned int)(m >> 32);
      jcL = (__popcll(mj) + 1 - jh) >> 1;
    }
  }
  __syncthreads();
  int jc = jcL;
  if (jc == 0) return;
  unsigned long long kadj = (unsigned long long)kadjLo |
                            ((unsigned long long)kadjHi << 32);
  float nmx = nmax[b*Nn + i];
  const float4* ag4 = (const float4*)(agg + (size_t)(b*Nn + i)*Ff);
  float aggf = agg[(b*Nn + i)*Ff + f];

  int NR = (jc + 7) >> 3;   // 8 j-slots per 256-thread round
  for (int r = 0; r < NR; ++r) {
    int slot = (tid >> 5) + r*8;
    bool act = slot < jc;
    int j = jlistL[act ? slot : 0];
    int p = i*(i-1)/2 + j;
    size_t eoff = ((size_t)(b*Nn + i)*Nn + j)*Ff + f;

    float wb = -1.0e30f, wcf = 0.f, un = 0.f, z = 0.f, mo_f = 0.f;
    float4 u[8];
#pragma unroll
    for (int q=0;q<8;++q) u[q] = make_float4(0.f,0.f,0.f,0.f);
    if (act) {
      const float4* u4 = (const float4*)&u_z[(((size_t)i*Nn + j)*Ff + f)*Ff];
#pragma unroll
      for (int q=0;q<8;++q) u[q] = u4[q];
      wb  = wzxb[eoff];
      wcf = wcxb[eoff];
#pragma unroll
      for (int q=0;q<8;++q){
        float4 a=u[q];
        un = fmaf(a.x,a.x,un); un = fmaf(a.y,a.y,un);
        un = fmaf(a.z,a.z,un); un = fmaf(a.w,a.w,un);
      }
      un = sqrtf(un);
      // z = sigmoid(wb + u . (agg - mf_prev[i,j]))
      const float4* mp4 = (const float4*)(mfp + eoff - f);
      float d = 0.f;
#pragma unroll
      for (int q=0;q<8;++q){
        float4 ag = ag4[q], mm = mp4[q];
        float mx = ag.x - mm.x, my = ag.y - mm.y;
        float mz = ag.z - mm.z, mw = ag.w - mm.w;
        d = fmaf(u[q].x,mx,d); d = fmaf(u[q].y,my,d);
        d = fmaf(u[q].z,mz,d); d = fmaf(u[q].w,mw,d);
      }
      z = sigmoidf_(wb + d);
      mo_f = aggf - mfp[eoff];
    }

    // per-j conservative screen: max_f wb + unfmax*nmax < 15.5 -> no gate
    // can reach the sigmoid==1.0 region (>=16.6) for ANY (f,k) of this j.
    float wbm = wb;
    wbm = fmaxf(wbm, __shfl_xor(wbm,1));  wbm = fmaxf(wbm, __shfl_xor(wbm,2));
    wbm = fmaxf(wbm, __shfl_xor(wbm,4));  wbm = fmaxf(wbm, __shfl_xor(wbm,8));
    wbm = fmaxf(wbm, __shfl_xor(wbm,16));
    bool fireH = act && (wbm + unfmax[p]*nmx >= 15.5f);

    float gs = 0.f;
    if (__any(fireH)) {
      unsigned long long kk = kadj & ~(1ull << j);  // j differs per half: mask
      // NOTE: halves have different j; clear own j per half via skip below.
      kk = kadj;
      while (kk) {
        int k = __builtin_ctzll(kk);
        kk &= kk - 1;
        int hi = i > k ? i : k, lo = i > k ? k : i;
        int pk = hi*(hi-1)/2 + lo;
        float nk = nrmp[pk*8 + b];
        unsigned long long sb = __ballot(fireH && (wb + un*nk >= 15.5f));
        if (((sb >> h32) & 0xFFFFFFFFull) != 0ull) {
          const float* Mr = mfp + ((size_t)(b*Nn + hi)*Nn + lo)*Ff;
          const float4* mk4 = (const float4*)Mr;
          float dd = 0.f;
#pragma unroll
          for (int q=0;q<8;++q){
            float4 m = mk4[q];
            dd = fmaf(u[q].x,m.x,dd); dd = fmaf(u[q].y,m.y,dd);
            dd = fmaf(u[q].z,m.z,dd); dd = fmaf(u[q].w,m.w,dd);
          }
          float v = wb + dd;
          if (act && k != j && v >= 16.0f &&
              (v > 17.5f || sigmoidf_(v) >= 1.0f)) gs += Mr[f];
        }
      }
    }

    // rare fire path: r_msg + second u_c dot via in-half shuffles (no LDS)
    unsigned long long gb = __ballot(gs != 0.0f);
    bool rf = ((gb >> h32) & 0xFFFFFFFFull) != 0ull;
    float d2 = 0.f;
    if (rf) {
      float4 uc[8];
      const float4* uc4 = (const float4*)&u_c[(((size_t)i*Nn + j)*Ff + f)*Ff];
#pragma unroll
      for (int q=0;q<8;++q) uc[q]=uc4[q];
      float rm = 0.f;
#pragma unroll
      for (int g = 0; g < 32; ++g)
        rm = fmaf(VCE(uc,g), __shfl(gs, h32 + g), rm);
      float dd2 = 0.f;
#pragma unroll
      for (int g = 0; g < 32; ++g)
        dd2 = fmaf(VCE(uc,g), __shfl(rm, h32 + g), dd2);
      d2 = dd2;
    }

    if (act) {
      float cur = tanhf(wcf + d2);
      float mfv = (1.0f - z)*mo_f + z*cur;
      mfn[eoff] = mfv;
      float ss = mfv*mfv;
      ss += __shfl_xor(ss,1); ss += __shfl_xor(ss,2); ss += __shfl_xor(ss,4);
      ss += __shfl_xor(ss,8); ss += __shfl_xor(ss,16);
      if (f == 0) nrmn[p*8 + b] = sqrtf(ss);
    }
  }
}

// ---- enc = relu(u_node.x + u_msg.msg_sum); msg_sum == agg of final mf ----
__global__ __launch_bounds__(64) void finalize_enc(
    const float* __restrict__ x,
    const float* __restrict__ agg,
    const float* __restrict__ u_node,
    const float* __restrict__ u_msg,
    float* __restrict__ enc) {
  int bi = blockIdx.x;
  int b = bi >> 6, i = bi & 63;
  int l = threadIdx.x, f = l & 31, h = l >> 5;
  __shared__ __align__(16) float vecL[2][Ff];
  if (l < 32)      vecL[0][l]      = x[(b*Nn + i)*Ff + l];
  else             vecL[1][l - 32] = agg[(b*Nn + i)*Ff + (l - 32)];
  __syncthreads();
  const float* Urow = (h == 0) ? &u_node[((size_t)i*Ff + f)*Ff]
                               : &u_msg [((size_t)i*Ff + f)*Ff];
  const float4* w4 = (const float4*)Urow;
  float4 w[8];
#pragma unroll
  for (int q=0;q<8;++q) w[q]=w4[q];
  float d = dot32(w, vecL[h]);
  float dO = __shfl(d, l ^ 32);
  if (l < 32) enc[(b*Nn + i)*Ff + f] = fmaxf(d + dO, 0.0f);
}

// ---- output linear + sigmoid: one wave per (b, o) ----
__global__ __launch_bounds__(64) void linear_out(
    const float* __restrict__ enc,
    const float* __restrict__ lin_w,
    const float* __restrict__ lin_b,
    float* __restrict__ out) {
  int b = blockIdx.x >> 7;
  int o = blockIdx.x & 127;
  int l = threadIdx.x;
  const float4* w4 = (const float4*)&lin_w[(size_t)o*(Nn*Ff)];
  const float4* e4 = (const float4*)&enc[(size_t)b*(Nn*Ff)];
  float acc = 0.f;
#pragma unroll
  for (int q = 0; q < 8; ++q) {
    float4 w = w4[q*64 + l], e = e4[q*64 + l];
    acc = fmaf(w.x,e.x,acc); acc = fmaf(w.y,e.y,acc);
    acc = fmaf(w.z,e.z,acc); acc = fmaf(w.w,e.w,acc);
  }
  acc += __shfl_xor(acc, 1);  acc += __shfl_xor(acc, 2);
  acc += __shfl_xor(acc, 4);  acc += __shfl_xor(acc, 8);
  acc += __shfl_xor(acc, 16); acc += __shfl_xor(acc, 32);
  if (l == 0) out[b*OUTn + o] = sigmoidf_(acc + lin_b[o]);
}

extern "C" void kernel_launch(void* const* d_in, const int* in_sizes, int n_in,
                              void* d_out, int out_size, void* d_ws, size_t ws_size,
                              hipStream_t stream) {
  const float* x      = (const float*)d_in[0];
  const float* A      = (const float*)d_in[1];
  const float* w_z    = (const float*)d_in[2];
  const float* w_c    = (const float*)d_in[3];
  const float* u_z    = (const float*)d_in[4];
  const float* u_c    = (const float*)d_in[5];
  const float* b_z    = (const float*)d_in[6];
  const float* b_c    = (const float*)d_in[7];
  const float* u_node = (const float*)d_in[8];
  const float* u_msg  = (const float*)d_in[9];
  const float* lin_w  = (const float*)d_in[10];
  const float* lin_b  = (const float*)d_in[11];
  float* out = (float*)d_out;
  float* ws  = (float*)d_ws;

  const size_t SZ = (size_t)Bb*Nn*Nn*Ff;      // 1,048,576 floats
  float* wzxb   = ws;
  float* wcxb   = wzxb + SZ;
  float* mf0    = wcxb + SZ;
  float* mf1    = mf0  + SZ;
  float* nrm0   = mf1  + SZ;                  // NPAIR*8
  float* nrm1   = nrm0 + (size_t)NPAIR*8;
  float* unfmax = nrm1 + (size_t)NPAIR*8;     // NPAIR
  float* agg    = unfmax + NPAIR;             // 8*64*32
  float* nmax   = agg  + (size_t)Bb*Nn*Ff;    // 8*64
  float* enc    = nmax + (size_t)Bb*Nn;       // 8*64*32

  precompute_pair<<<NPAIR, 64, 0, stream>>>(x, w_z, w_c, u_z, b_z, b_c,
                                            wzxb, wcxb, mf0, nrm0, unfmax);

  float* mfR = mf0;  float* nrR = nrm0;
  float* mfW = mf1;  float* nrW = nrm1;
  for (int t = 1; t < Tt; ++t) {
    gather_agg<<<Bb*Nn, 64, 0, stream>>>(A, mfR, nrR, agg, nmax);
    edge_update<<<dim3(Bb, Nn, 2), 256, 0, stream>>>(A, u_z, u_c, wzxb, wcxb,
                                                     unfmax, agg, nmax,
                                                     mfR, nrR, mfW, nrW);
    float* tm = mfR; mfR = mfW; mfW = tm;
    float* tn = nrR; nrR = nrW; nrW = tn;
  }
  gather_agg<<<Bb*Nn, 64, 0, stream>>>(A, mfR, nrR, agg, nmax);  // msg_sum
  finalize_enc<<<Bb*Nn, 64, 0, stream>>>(x, agg, u_node, u_msg, enc);
  linear_out<<<Bb*OUTn, 64, 0, stream>>>(enc, lin_w, lin_b, out);
}